// Round 3
// baseline (121.029 us; speedup 1.0000x reference)
//
#include <hip/hip_runtime.h>

// RelationalDense: out[n,:] = feat[n,:] @ W[rel[n]] + bias,  W = einsum('rb,bfo', lin, V)
// N=65536, F=64, U=64, R=25, B=8.
//
// Strategy: bucket rows by relation so every wave is relation-uniform; the
// per-row 16 KB W read becomes a wave-uniform scalar (SMEM) broadcast instead
// of a 23-way cacheline gather (~1 GB of L1/L2 traffic = 26+ us).
// R2/R3: one thread per ROW (64 acc regs) -> features read exactly once
// (R1's 4-quarter split read each row 4x = 67 MB L1 / 4.2M line transactions).
// Count-guarded buckets eliminate the 0.4 MB idx_sorted memset dispatch.
// R3 fix: nontemporal builtins need clang native vectors, not HIP float4.

typedef float v4f __attribute__((ext_vector_type(4)));

#define NN 65536
#define FF 64
#define UU 64
#define RR 25
#define BB 8
#define CAP 4096                 // slots per bucket; mean fill 2621, +29 sigma safe
#define NSLOT (RR * CAP)         // 102400

// ws layout:
//   [0, NSLOT*4)           idx_sorted (int)  -- NOT memset; validity = pos < cnt
//   [NSLOT*4, +128)        cursors (25 ints), memset 0; == bucket counts after k_prep
//   [W_OFF, +R*F*U*4)      W fp32
#define IDX_OFF 0
#define CUR_OFF (NSLOT * 4)
#define W_OFF   (NSLOT * 4 + 128)
#define WS_NEED ((size_t)(W_OFF + RR * FF * UU * 4))

// ---------------------------------------------------------------------------
// K1: fused W precompute (blocks [0,400)) + bucket scatter (blocks [400,656))
// ---------------------------------------------------------------------------
__global__ __launch_bounds__(256) void k_prep(
    const float* __restrict__ kern,   // [B,F,U]
    const float* __restrict__ lin,    // [R,B]
    const int*   __restrict__ rel,    // [N]
    float*       __restrict__ W,      // [R,F,U]
    int*         __restrict__ idx_sorted,
    int*         __restrict__ cursors) {
  const int wblocks = (RR * FF * UU) / 256;  // 400
  int bid = blockIdx.x;
  if (bid < wblocks) {
    // W[r, fo] = sum_b lin[r,b] * V[b, fo]; idx>>12 is wave-uniform (4096%64==0)
    int idx = bid * 256 + threadIdx.x;
    int r  = __builtin_amdgcn_readfirstlane(idx >> 12);
    int fo = idx & (FF * UU - 1);
    float acc = 0.f;
#pragma unroll
    for (int b = 0; b < BB; ++b)
      acc += lin[r * BB + b] * kern[b * (FF * UU) + fo];
    W[idx] = acc;
  } else {
    // scatter: block of 256 rows -> LDS histogram -> reserve global range -> place
    int sb  = bid - wblocks;
    int tid = threadIdx.x;
    __shared__ int cnt[RR], base[RR], lcur[RR];
    if (tid < RR) { cnt[tid] = 0; lcur[tid] = 0; }
    __syncthreads();
    int row = sb * 256 + tid;
    int r = rel[row];
    atomicAdd(&cnt[r], 1);
    __syncthreads();
    if (tid < RR) base[tid] = atomicAdd(&cursors[tid], cnt[tid]);
    __syncthreads();
    int loc = atomicAdd(&lcur[r], 1);
    idx_sorted[r * CAP + base[r] + loc] = row;
  }
}

// ---------------------------------------------------------------------------
// K2: main compute. ONE THREAD PER ROW: 64 outputs in registers, features
// loaded exactly once (16 x dwordx4 per lane). Block = 1 wave (64 threads);
// CAP % 64 == 0 so relation r is wave-uniform -> W/bias scalarize to s_load.
// ---------------------------------------------------------------------------
__global__ __launch_bounds__(64) void k_main(
    const float* __restrict__ features,  // [N,F]
    const float* __restrict__ bias,      // [U]
    const float* __restrict__ W,         // [R,F,U]
    const int*   __restrict__ idx_sorted,
    const int*   __restrict__ cursors,   // bucket counts after k_prep
    float*       __restrict__ out) {     // [N,U]
  int slot = blockIdx.x * 64 + threadIdx.x;
  int r    = __builtin_amdgcn_readfirstlane(slot >> 12);  // uniform per wave
  int pos  = slot & (CAP - 1);
  int cnt  = cursors[r];                                  // uniform -> s_load
  if (pos >= cnt) return;                                 // empty tail of bucket
  int row  = idx_sorted[slot];

  const float* Wr = W + r * (FF * UU);                    // uniform -> SMEM
  const v4f*   fr = reinterpret_cast<const v4f*>(features + (size_t)row * FF);

  v4f fv[16];
#pragma unroll
  for (int i = 0; i < 16; ++i)
    fv[i] = __builtin_nontemporal_load(fr + i);           // row read exactly once

  float acc[UU];
#pragma unroll
  for (int j = 0; j < UU; ++j) acc[j] = bias[j];          // uniform -> s_load

#pragma unroll
  for (int fc = 0; fc < 16; ++fc) {
#pragma unroll
    for (int c = 0; c < 4; ++c) {
      int f = fc * 4 + c;
      float fs = fv[fc][c];
#pragma unroll
      for (int j = 0; j < UU; ++j)
        acc[j] += fs * Wr[f * UU + j];                    // v_fmac, SGPR W operand
    }
  }

  v4f* o4 = reinterpret_cast<v4f*>(out + (size_t)row * UU);
#pragma unroll
  for (int j4 = 0; j4 < 16; ++j4) {
    v4f v = {acc[4 * j4], acc[4 * j4 + 1], acc[4 * j4 + 2], acc[4 * j4 + 3]};
    __builtin_nontemporal_store(v, o4 + j4);              // written exactly once
  }
}

// ---------------------------------------------------------------------------
// Fallback (no workspace): compute W_r on the fly per row. Safety net only.
// ---------------------------------------------------------------------------
__global__ __launch_bounds__(256) void k_fallback(
    const float* __restrict__ features,
    const int*   __restrict__ rel,
    const float* __restrict__ kern,
    const float* __restrict__ lin,
    const float* __restrict__ bias,
    float*       __restrict__ out) {
  int tid = threadIdx.x;
  int row = blockIdx.x * 64 + (tid & 63);
  int q   = __builtin_amdgcn_readfirstlane(tid >> 6);
  int r   = rel[row];
  float cf[BB];
#pragma unroll
  for (int b = 0; b < BB; ++b) cf[b] = lin[r * BB + b];
  const v4f* fr = reinterpret_cast<const v4f*>(features + (size_t)row * FF);
  v4f fv[16];
#pragma unroll
  for (int i = 0; i < 16; ++i) fv[i] = fr[i];
  float acc[16];
#pragma unroll
  for (int j = 0; j < 16; ++j) acc[j] = bias[q * 16 + j];
#pragma unroll
  for (int fc = 0; fc < 16; ++fc) {
#pragma unroll
    for (int c = 0; c < 4; ++c) {
      int f = fc * 4 + c;
      float fs = fv[fc][c];
      float wf[16];
#pragma unroll
      for (int j = 0; j < 16; ++j) wf[j] = 0.f;
#pragma unroll
      for (int b = 0; b < BB; ++b) {
        const float* Vb = kern + b * (FF * UU) + f * UU + q * 16;
#pragma unroll
        for (int j = 0; j < 16; ++j) wf[j] += cf[b] * Vb[j];
      }
#pragma unroll
      for (int j = 0; j < 16; ++j) acc[j] += fs * wf[j];
    }
  }
  v4f* o4 = reinterpret_cast<v4f*>(out + (size_t)row * UU + q * 16);
#pragma unroll
  for (int j4 = 0; j4 < 4; ++j4) {
    v4f v = {acc[4 * j4], acc[4 * j4 + 1], acc[4 * j4 + 2], acc[4 * j4 + 3]};
    o4[j4] = v;
  }
}

extern "C" void kernel_launch(void* const* d_in, const int* in_sizes, int n_in,
                              void* d_out, int out_size, void* d_ws, size_t ws_size,
                              hipStream_t stream) {
  const float* features  = (const float*)d_in[0];
  const int*   relations = (const int*)d_in[1];
  const float* kern      = (const float*)d_in[2];
  const float* lin       = (const float*)d_in[3];
  const float* bias      = (const float*)d_in[4];
  float* out = (float*)d_out;

  if (ws_size >= WS_NEED) {
    char*  ws         = (char*)d_ws;
    int*   idx_sorted = (int*)(ws + IDX_OFF);
    int*   cursors    = (int*)(ws + CUR_OFF);
    float* W          = (float*)(ws + W_OFF);
    (void)hipMemsetAsync(cursors, 0, RR * sizeof(int), stream);   // 100 B only
    k_prep<<<(RR * FF * UU) / 256 + NN / 256, 256, 0, stream>>>(
        kern, lin, relations, W, idx_sorted, cursors);
    k_main<<<NSLOT / 64, 64, 0, stream>>>(features, bias, W, idx_sorted, cursors, out);
  } else {
    k_fallback<<<NN / 64, 256, 0, stream>>>(features, relations, kern, lin, bias, out);
  }
}

// Round 4
// 99.408 us; speedup vs baseline: 1.2175x; 1.2175x over previous
//
#include <hip/hip_runtime.h>

// RelationalDense: out[n,:] = feat[n,:] @ W[rel[n]] + bias,  W = einsum('rb,bfo', lin, V)
// N=65536, F=64, U=64, R=25, B=8.
//
// Strategy: bucket rows by relation so every wave is relation-uniform; the
// per-row 16 KB W read becomes a wave-uniform scalar (SMEM) broadcast instead
// of a 23-way cacheline gather (~1 GB of L1/L2 traffic).
// R4: R3's 1-thread/row spilled (VGPR capped 60 < 140 needed -> 52 MB scratch
// writes, 1.56 waves/SIMD TLP). Back to wave-uniform quarter layout: wave =
// 64 slots x quarter(q=tid>>6); acc[16] + 16-float feature chunks keeps
// ~50-80 VGPR live; launch_bounds(256,4) caps at 128 so no 60-VGPR repeat.

typedef float v4f __attribute__((ext_vector_type(4)));

#define NN 65536
#define FF 64
#define UU 64
#define RR 25
#define BB 8
#define CAP 4096                 // slots per bucket; mean fill 2621, +29 sigma safe
#define NSLOT (RR * CAP)         // 102400

// ws layout:
//   [0, NSLOT*4)           idx_sorted (int)  -- NOT memset; validity = pos < cnt
//   [NSLOT*4, +128)        cursors (25 ints), memset 0; == bucket counts after k_prep
//   [W_OFF, +R*F*U*4)      W fp32
#define IDX_OFF 0
#define CUR_OFF (NSLOT * 4)
#define W_OFF   (NSLOT * 4 + 128)
#define WS_NEED ((size_t)(W_OFF + RR * FF * UU * 4))

// ---------------------------------------------------------------------------
// K1: fused W precompute (blocks [0,400)) + bucket scatter (blocks [400,656))
// ---------------------------------------------------------------------------
__global__ __launch_bounds__(256) void k_prep(
    const float* __restrict__ kern,   // [B,F,U]
    const float* __restrict__ lin,    // [R,B]
    const int*   __restrict__ rel,    // [N]
    float*       __restrict__ W,      // [R,F,U]
    int*         __restrict__ idx_sorted,
    int*         __restrict__ cursors) {
  const int wblocks = (RR * FF * UU) / 256;  // 400
  int bid = blockIdx.x;
  if (bid < wblocks) {
    // W[r, fo] = sum_b lin[r,b] * V[b, fo]; idx>>12 is wave-uniform (4096%64==0)
    int idx = bid * 256 + threadIdx.x;
    int r  = __builtin_amdgcn_readfirstlane(idx >> 12);
    int fo = idx & (FF * UU - 1);
    float acc = 0.f;
#pragma unroll
    for (int b = 0; b < BB; ++b)
      acc += lin[r * BB + b] * kern[b * (FF * UU) + fo];
    W[idx] = acc;
  } else {
    // scatter: block of 256 rows -> LDS histogram -> reserve global range -> place
    int sb  = bid - wblocks;
    int tid = threadIdx.x;
    __shared__ int cnt[RR], base[RR], lcur[RR];
    if (tid < RR) { cnt[tid] = 0; lcur[tid] = 0; }
    __syncthreads();
    int row = sb * 256 + tid;
    int r = rel[row];
    atomicAdd(&cnt[r], 1);
    __syncthreads();
    if (tid < RR) base[tid] = atomicAdd(&cursors[tid], cnt[tid]);
    __syncthreads();
    int loc = atomicAdd(&lcur[r], 1);
    idx_sorted[r * CAP + base[r] + loc] = row;
  }
}

// ---------------------------------------------------------------------------
// K2: main compute. Block 256 = 4 waves over the SAME 64 slots; wave w handles
// output quarter q=w (wave-uniform) -> W/bias scalarize to s_load broadcasts.
// acc[16] per thread; features consumed in 4 chunks of 16 floats so only
// ~16 fv regs live alongside acc. CAP%64==0 -> r uniform per wave.
// ---------------------------------------------------------------------------
__global__ __launch_bounds__(256, 4) void k_main(
    const float* __restrict__ features,  // [N,F]
    const float* __restrict__ bias,      // [U]
    const float* __restrict__ W,         // [R,F,U]
    const int*   __restrict__ idx_sorted,
    const int*   __restrict__ cursors,   // bucket counts after k_prep
    float*       __restrict__ out) {     // [N,U]
  int tid  = threadIdx.x;
  int slot = blockIdx.x * 64 + (tid & 63);
  int q    = __builtin_amdgcn_readfirstlane(tid >> 6);    // 0..3, uniform per wave
  int r    = __builtin_amdgcn_readfirstlane(slot >> 12);  // uniform per wave
  int pos  = slot & (CAP - 1);
  int cnt  = cursors[r];                                  // uniform -> s_load
  if (pos >= cnt) return;                                 // empty tail of bucket
  int row  = idx_sorted[slot];

  const float* Wq = W + r * (FF * UU) + q * 16;           // uniform -> SMEM
  const v4f*   fr = reinterpret_cast<const v4f*>(features + (size_t)row * FF);

  float acc[16];
#pragma unroll
  for (int j = 0; j < 16; ++j) acc[j] = bias[q * 16 + j]; // uniform -> s_load

#pragma unroll
  for (int ch = 0; ch < 4; ++ch) {                        // 16 features per chunk
    v4f fv[4];
#pragma unroll
    for (int k = 0; k < 4; ++k) fv[k] = fr[ch * 4 + k];
#pragma unroll
    for (int k = 0; k < 4; ++k) {
#pragma unroll
      for (int c = 0; c < 4; ++c) {
        int f = ch * 16 + k * 4 + c;
        float fs = fv[k][c];
#pragma unroll
        for (int j = 0; j < 16; ++j)
          acc[j] += fs * Wq[f * UU + j];                  // v_fmac, SGPR W operand
      }
    }
  }

  v4f* o4 = reinterpret_cast<v4f*>(out + (size_t)row * UU + q * 16);
#pragma unroll
  for (int j4 = 0; j4 < 4; ++j4) {
    v4f v = {acc[4 * j4], acc[4 * j4 + 1], acc[4 * j4 + 2], acc[4 * j4 + 3]};
    o4[j4] = v;
  }
}

// ---------------------------------------------------------------------------
// Fallback (no workspace): compute W_r on the fly per row. Safety net only.
// ---------------------------------------------------------------------------
__global__ __launch_bounds__(256) void k_fallback(
    const float* __restrict__ features,
    const int*   __restrict__ rel,
    const float* __restrict__ kern,
    const float* __restrict__ lin,
    const float* __restrict__ bias,
    float*       __restrict__ out) {
  int tid = threadIdx.x;
  int row = blockIdx.x * 64 + (tid & 63);
  int q   = __builtin_amdgcn_readfirstlane(tid >> 6);
  int r   = rel[row];
  float cf[BB];
#pragma unroll
  for (int b = 0; b < BB; ++b) cf[b] = lin[r * BB + b];
  const v4f* fr = reinterpret_cast<const v4f*>(features + (size_t)row * FF);
  float acc[16];
#pragma unroll
  for (int j = 0; j < 16; ++j) acc[j] = bias[q * 16 + j];
#pragma unroll
  for (int ch = 0; ch < 4; ++ch) {
    v4f fv[4];
#pragma unroll
    for (int k = 0; k < 4; ++k) fv[k] = fr[ch * 4 + k];
#pragma unroll
    for (int k = 0; k < 4; ++k) {
#pragma unroll
      for (int c = 0; c < 4; ++c) {
        int f = ch * 16 + k * 4 + c;
        float fs = fv[k][c];
        float wf[16];
#pragma unroll
        for (int j = 0; j < 16; ++j) wf[j] = 0.f;
#pragma unroll
        for (int b = 0; b < BB; ++b) {
          const float* Vb = kern + b * (FF * UU) + f * UU + q * 16;
#pragma unroll
          for (int j = 0; j < 16; ++j) wf[j] += cf[b] * Vb[j];
        }
#pragma unroll
        for (int j = 0; j < 16; ++j) acc[j] += fs * wf[j];
      }
    }
  }
  v4f* o4 = reinterpret_cast<v4f*>(out + (size_t)row * UU + q * 16);
#pragma unroll
  for (int j4 = 0; j4 < 4; ++j4) {
    v4f v = {acc[4 * j4], acc[4 * j4 + 1], acc[4 * j4 + 2], acc[4 * j4 + 3]};
    o4[j4] = v;
  }
}

extern "C" void kernel_launch(void* const* d_in, const int* in_sizes, int n_in,
                              void* d_out, int out_size, void* d_ws, size_t ws_size,
                              hipStream_t stream) {
  const float* features  = (const float*)d_in[0];
  const int*   relations = (const int*)d_in[1];
  const float* kern      = (const float*)d_in[2];
  const float* lin       = (const float*)d_in[3];
  const float* bias      = (const float*)d_in[4];
  float* out = (float*)d_out;

  if (ws_size >= WS_NEED) {
    char*  ws         = (char*)d_ws;
    int*   idx_sorted = (int*)(ws + IDX_OFF);
    int*   cursors    = (int*)(ws + CUR_OFF);
    float* W          = (float*)(ws + W_OFF);
    (void)hipMemsetAsync(cursors, 0, RR * sizeof(int), stream);   // 100 B only
    k_prep<<<(RR * FF * UU) / 256 + NN / 256, 256, 0, stream>>>(
        kern, lin, relations, W, idx_sorted, cursors);
    k_main<<<NSLOT / 64, 256, 0, stream>>>(features, bias, W, idx_sorted, cursors, out);
  } else {
    k_fallback<<<NN / 64, 256, 0, stream>>>(features, relations, kern, lin, bias, out);
  }
}